// Round 7
// baseline (139.410 us; speedup 1.0000x reference)
//
#include <hip/hip_runtime.h>
#include <hip/hip_bf16.h>

typedef __bf16 bf16x8 __attribute__((ext_vector_type(8)));
typedef float floatx4 __attribute__((ext_vector_type(4)));
typedef unsigned short u16;
typedef unsigned int u32;

#define HW 196      // 14*14
#define NB 8
#define NC 128
#define CL 480      // xfe row stride (u16)
#define WROW 12544  // u32 per (b,a1) row of W (= 25088 bf16 = 128c * 196p)

// ws offsets (bytes)
#define OFF_XFRSW 0            // 8 * 3584 uint4 = 458752 B  (A in MFMA-frag order)
#define OFF_XFE   458752       // 8*128*8*480*2 = 7864320 B  (8 shift-copies / row)
#define OFF_W     8323072      // 12845056 B
#define OFF_SUMS  21168128     // 32 B
#define OFF_Y     21168160     // 8*128*256*4 = 1048576 B   (post-ReLU conv out, fp32)
#define OFF_XBT   22216736     // 8*256*512*2 = 2097152 B   (x^T bf16: [b][pix][k])
#define OFF_WB    24313888     // 128*512*2   = 131072 B    (w bf16: [o][k])

// ---- Stage 0: cast x (transposed) and w to bf16 ----
// R6 lesson: the fp32 GEMM was ~30 us because each thread issued 512
// broadcast weight loads (t>>8 not provably wave-uniform -> v-loads).
// MFMA GEMM removes that; this kernel prepares bf16 operands.
// blocks 0..511: x-part; 512..543: w-part. 256 thr.
__global__ __launch_bounds__(256) void k_cast(const float* __restrict__ x,
                                              const float* __restrict__ wc,
                                              u16* __restrict__ xbT,
                                              u16* __restrict__ wb) {
  const int bid = blockIdx.x;
  const int t   = threadIdx.x;
  if (bid < 512) {
    const int gid = bid * 256 + t;
    const int pix = gid & 255;          // lanes -> consecutive pix: coalesced reads
    const int kc  = (gid >> 8) & 63;    // 8-k chunk
    const int b   = gid >> 14;
    union { u16 u[8]; uint4 v; } pk;
#pragma unroll
    for (int j = 0; j < 8; ++j) {
      union { __hip_bfloat16 h; u16 u; } cv;
      cv.h = __float2bfloat16(x[((size_t)(b * 512 + kc * 8 + j)) * 256 + pix]);
      pk.u[j] = cv.u;
    }
    ((uint4*)xbT)[(size_t)(b * 256 + pix) * 64 + kc] = pk.v;
  } else {
    const int wid = (bid - 512) * 256 + t;   // 0..8191, 8 elems each
    const float4* wf4 = (const float4*)wc;
    const float4 f0 = wf4[wid * 2], f1 = wf4[wid * 2 + 1];
    union { u16 u[8]; uint4 v; } pk;
    union { __hip_bfloat16 h; u16 u; } cv;
    cv.h = __float2bfloat16(f0.x); pk.u[0] = cv.u;
    cv.h = __float2bfloat16(f0.y); pk.u[1] = cv.u;
    cv.h = __float2bfloat16(f0.z); pk.u[2] = cv.u;
    cv.h = __float2bfloat16(f0.w); pk.u[3] = cv.u;
    cv.h = __float2bfloat16(f1.x); pk.u[4] = cv.u;
    cv.h = __float2bfloat16(f1.y); pk.u[5] = cv.u;
    cv.h = __float2bfloat16(f1.z); pk.u[6] = cv.u;
    cv.h = __float2bfloat16(f1.w); pk.u[7] = cv.u;
    ((uint4*)wb)[wid] = pk.v;
  }
}

// ---- Stage 1: 1x1-conv GEMM via MFMA 16x16x32 bf16 + ReLU -> Y[b][o][pix] fp32 ----
// grid (8 b, 4 pg-of-64-pix), 256 thr = 4 waves; wave -> 16-pix n-tile.
// A = w[o][k] (m=o), B = x^T[pix][k] (n=pix); both loaded as per-lane b128
// direct from global (L2-hot: wb 128 KB, xbT[b] 256 KB, XCD-local via b=bIdx.x%8).
__global__ __launch_bounds__(256) void k_conv(const u16* __restrict__ xbT,
                                              const u16* __restrict__ wb,
                                              float* __restrict__ Y) {
  const int b  = blockIdx.x;
  const int pg = blockIdx.y;
  const int t  = threadIdx.x;
  const int lane = t & 63, wv = t >> 6;
  const int n = lane & 15, quad = lane >> 4;
  const int pix0 = pg * 64 + wv * 16;

  const u16* xrow = xbT + ((size_t)(b * 256) + pix0 + n) * 512 + quad * 8;
  const u16* wrow = wb + (size_t)n * 512 + quad * 8;

  floatx4 acc[8];
#pragma unroll
  for (int at = 0; at < 8; ++at) acc[at] = (floatx4){0.f, 0.f, 0.f, 0.f};

#pragma unroll 4
  for (int kb = 0; kb < 16; ++kb) {
    const bf16x8 bv = *(const bf16x8*)(xrow + kb * 32);
#pragma unroll
    for (int at = 0; at < 8; ++at) {
      const bf16x8 av = *(const bf16x8*)(wrow + (size_t)(at * 16) * 512 + kb * 32);
      acc[at] = __builtin_amdgcn_mfma_f32_16x16x32_bf16(av, bv, acc[at], 0, 0, 0);
    }
  }

  // D[m=quad*4+rr][n] -> Y[b][o=at*16+quad*4+rr][pix0+n], fused ReLU
  float* Yb = Y + ((size_t)b * 128) * 256 + pix0 + n;
#pragma unroll
  for (int at = 0; at < 8; ++at)
#pragma unroll
    for (int rr = 0; rr < 4; ++rr)
      Yb[(at * 16 + quad * 4 + rr) * 256] = fmaxf(acc[at][rr], 0.f);
}

// ---- Stage 1b: 3x3 Gaussian blur + bf16 + operand repack; emits:
//  xfr_sw[b][kb7][at8][quad4][m16][j8]  = reversed row (A-operand, frag order)
//  xfe[b][c][S8][CL]                    = row_c[(m+S) mod 196] (B shift table)
// grid (8 b, 32 rg-of-4-rows), 256 thr = pixel.
__global__ __launch_bounds__(256) void k_blur(const float* __restrict__ Y,
                                              uint4* __restrict__ xfr_sw,
                                              u16* __restrict__ xfe) {
  const int b  = blockIdx.x;
  const int rg = blockIdx.y;       // rows rg*4 .. +3
  const int t  = threadIdx.x;      // pixel

  __shared__ float ybuf[4][256];
  __shared__ u16 ydup[4][592];     // blurred row bf16, replicated 3x (idx 0..587)

#pragma unroll
  for (int oo = 0; oo < 4; ++oo)
    ybuf[oo][t] = Y[((size_t)(b * 128) + rg * 4 + oo) * 256 + t];  // already ReLU'd
  __syncthreads();

  const float GC = 0.63661977236758138f;   // gaussian var 0.25
  const float GE = GC * 0.13533528323661270f;
  const float GD = GC * 0.018315638888734179f;

  if (t < HW) {
    const int h = t / 14, w2 = t - h * 14;
#pragma unroll
    for (int oo = 0; oo < 4; ++oo) {
      const float* yb = &ybuf[oo][h * 16 + w2];
      float v = GD * (yb[0] + yb[2] + yb[32] + yb[34])
              + GE * (yb[1] + yb[16] + yb[18] + yb[33])
              + GC * yb[17];
      union { __hip_bfloat16 h2; u16 u; } cv; cv.h2 = __float2bfloat16(v);
      ydup[oo][t] = cv.u; ydup[oo][t + 196] = cv.u; ydup[oo][t + 392] = cv.u;
    }
  }
  __syncthreads();

  // xfr_sw: per row 28 uint4 (g = kb*4+quad), Arev[k] = y[(196-k)%196], 0 for k>=196
  if (t < 112) {
    const int oo = t / 28;
    const int g  = t - oo * 28;
    const int kb = g >> 2, quad = g & 3;
    const int c  = rg * 4 + oo;
    const int at = c >> 4, m = c & 15;
    union { u16 u[8]; uint4 v; } pk;
#pragma unroll
    for (int j = 0; j < 8; ++j) {
      const int k = g * 8 + j;
      pk.u[j] = (k < HW) ? ydup[oo][HW - k] : (u16)0;
    }
    xfr_sw[b * 3584 + ((kb * 8 + at) * 4 + quad) * 16 + m] = pk.v;
  }

  // xfe: 4 rows x 8 shifts x 60 uint4
  uint4* xfe4 = (uint4*)xfe;
  for (int idx = t; idx < 4 * 8 * 60; idx += 256) {
    const int oo = idx / 480;
    const int rem = idx - oo * 480;
    const int S = rem / 60;
    const int g = rem - S * 60;
    const int c = rg * 4 + oo;
    union { u16 u[8]; uint4 v; } pk;
#pragma unroll
    for (int j = 0; j < 8; ++j) pk.u[j] = ydup[oo][g * 8 + j + S];  // <= 487 < 588
    xfe4[((size_t)(b * NC + c) * 8 + S) * 60 + g] = pk.v;
  }
}

// ---- Stage 2: circular correlation via MFMA 16x16x32; conflict-free LDS A,
// B direct-from-global (L1/L2-hot); in-reg 4:1 a-fold; bf16 W[b][a1][c*196+p] ----
// grid (8 b, 64 cpair); 256 threads = 4 waves.  (unchanged since R4, ~4-5 us)
__global__ __launch_bounds__(256, 2) void k_cooc(const uint4* __restrict__ xfr_sw,
                                                 const u16* __restrict__ xfe,
                                                 u32* __restrict__ W) {
  const int b     = blockIdx.x;
  const int cpair = blockIdx.y;
  const int t     = threadIdx.x;

  __shared__ __align__(16) uint4 Abuf[3584];   // 57344 B, frag order
  __shared__ __align__(16) u16 Obuf[32 * 200]; // 12800 B

  { // flat coalesced staging (xfr_sw is XCD-L2 resident)
    const uint4* src = xfr_sw + b * 3584;
    for (int j = t; j < 3584; j += 256) Abuf[j] = src[j];
  }
  __syncthreads();

  const int lane = t & 63;
  const int wv   = t >> 6;       // p-tiles {wv, wv+4, wv+8} (+12 for wave 0)
  const int n    = lane & 15;
  const int quad = lane >> 4;
  const u16* xbase = xfe + ((size_t)(b * NC) * 8) * CL + (n & 8) + quad * 8
                   + (size_t)(n & 7) * CL;

  for (int c2 = 0; c2 < 2; ++c2) {
    const int c = cpair * 2 + c2;
    const u16* xc = xbase + (size_t)c * (8 * CL);

    floatx4 acc[8][4];
#pragma unroll
    for (int at = 0; at < 8; ++at)
#pragma unroll
      for (int j = 0; j < 4; ++j) acc[at][j] = (floatx4){0.f, 0.f, 0.f, 0.f};

    for (int kb = 0; kb < 7; ++kb) {
      bf16x8 af[8];
#pragma unroll
      for (int at = 0; at < 8; ++at)   // lane-contiguous: base + lane*16B, no conflicts
        af[at] = *((const bf16x8*)&Abuf[(kb * 8 + at) * 64 + lane]);

#define DO_PT(JC)                                                                \
      {                                                                          \
        const int p0 = (wv + 4 * (JC)) * 16;                                     \
        const bf16x8 bv = *((const bf16x8*)&xc[p0 + kb * 32]);                   \
        _Pragma("unroll")                                                        \
        for (int at = 0; at < 8; ++at)                                           \
          acc[at][JC] = __builtin_amdgcn_mfma_f32_16x16x32_bf16(af[at], bv,      \
                                                                acc[at][JC], 0, 0, 0); \
      }
      DO_PT(0)
      DO_PT(1)
      DO_PT(2)
      if (wv == 0) { DO_PT(3) }
#undef DO_PT
    }

#define EPI(JC)                                                                  \
    {                                                                            \
      const int p = (wv + 4 * (JC)) * 16 + n;                                    \
      if (p < HW) {                                                              \
        _Pragma("unroll")                                                        \
        for (int a0t = 0; a0t < 2; ++a0t) {                                      \
          _Pragma("unroll")                                                      \
          for (int rr = 0; rr < 4; ++rr) {                                       \
            float v = fmaxf(fmaxf(acc[a0t][JC][rr], acc[a0t + 2][JC][rr]),       \
                            fmaxf(acc[a0t + 4][JC][rr], acc[a0t + 6][JC][rr]));  \
            const int a1 = a0t * 16 + quad * 4 + rr;                             \
            union { __hip_bfloat16 h; u16 u; } cv;                               \
            cv.h = __float2bfloat16(v);                                          \
            Obuf[a1 * 200 + p] = cv.u;                                           \
          }                                                                      \
        }                                                                        \
      }                                                                          \
    }
    EPI(0)
    EPI(1)
    EPI(2)
    if (wv == 0) { EPI(3) }
#undef EPI
    __syncthreads();

    { // coalesced store: 32 rows x 98 u32 into W[b][a1][c*98 + col]
      const u32* O32 = (const u32*)Obuf;
      u32* Wb = W + ((size_t)b * 32) * WROW + c * 98;
      for (int j = t; j < 32 * 98; j += 256) {
        const int row = (int)(((unsigned)j * 10700u) >> 20);   // j / 98
        const int col = j - row * 98;
        Wb[row * WROW + col] = O32[row * 100 + col];
      }
    }
    __syncthreads();
  }
}

// ---- Stage 3: per-slot max over 49 contributors (coalesced) + sqrt + batch sum ----
__global__ __launch_bounds__(256) void k_max(const u32* __restrict__ W,
                                             float* __restrict__ out,
                                             float* __restrict__ sums) {
  const int gid = blockIdx.x * 256 + threadIdx.x;   // 0..65535
  const int b  = gid >> 13;
  const int r0 = (gid & 8191) << 1;
  const u32* Wb = W + (size_t)b * 32 * WROW;

  float m0 = 0.f, m1 = 0.f;
#pragma unroll 4
  for (int a1 = 0; a1 < 32; ++a1) {
    const int s = (r0 - ((a1 * 8704) & 16383)) & 16383;   // even
    const u32 v = Wb[a1 * WROW + (s >> 1)];
    m0 = fmaxf(m0, __uint_as_float((v & 0xffffu) << 16));
    m1 = fmaxf(m1, __uint_as_float(v & 0xffff0000u));
    if (s < 8704) {   // second contributor s+16384 < 25088
      const u32 v2 = Wb[a1 * WROW + ((s + 16384) >> 1)];
      m0 = fmaxf(m0, __uint_as_float((v2 & 0xffffu) << 16));
      m1 = fmaxf(m1, __uint_as_float(v2 & 0xffff0000u));
    }
  }
  const int o = b * 16384 + r0;
  out[o]     = sqrtf(m0);
  out[o + 1] = sqrtf(m1);

  float s2 = m0 + m1;
#pragma unroll
  for (int off = 32; off > 0; off >>= 1) s2 += __shfl_down(s2, off, 64);
  __shared__ float part[4];
  if ((threadIdx.x & 63) == 0) part[threadIdx.x >> 6] = s2;
  __syncthreads();
  if (threadIdx.x == 0)
    atomicAdd(&sums[b], part[0] + part[1] + part[2] + part[3]);
}

// ---- Stage 4: normalize ----
__global__ __launch_bounds__(256) void k_norm(const float* __restrict__ sums,
                                              float* __restrict__ out) {
  const int gid = blockIdx.x * 256 + threadIdx.x;
  const int b = gid >> 14;
  out[gid] = out[gid] / (sums[b] + 1e-11f);
}

extern "C" void kernel_launch(void* const* d_in, const int* in_sizes, int n_in,
                              void* d_out, int out_size, void* d_ws, size_t ws_size,
                              hipStream_t stream) {
  const float* x  = (const float*)d_in[0];   // (8,512,16,16) fp32
  const float* wc = (const float*)d_in[1];   // (128,512) fp32

  char* ws = (char*)d_ws;
  uint4* xfr_sw = (uint4*)(ws + OFF_XFRSW);
  u16*   xfe    = (u16*)(ws + OFF_XFE);
  u32*   W      = (u32*)(ws + OFF_W);
  float* sums   = (float*)(ws + OFF_SUMS);
  float* Y      = (float*)(ws + OFF_Y);
  u16*   xbT    = (u16*)(ws + OFF_XBT);
  u16*   wb     = (u16*)(ws + OFF_WB);

  hipMemsetAsync(sums, 0, NB * sizeof(float), stream);
  k_cast<<<544, 256, 0, stream>>>(x, wc, xbT, wb);
  k_conv<<<dim3(NB, 4), 256, 0, stream>>>(xbT, wb, Y);
  k_blur<<<dim3(NB, 32), 256, 0, stream>>>(Y, xfr_sw, xfe);
  k_cooc<<<dim3(NB, 64), 256, 0, stream>>>(xfr_sw, xfe, W);
  k_max<<<256, 256, 0, stream>>>(W, (float*)d_out, sums);
  k_norm<<<(NB * 16384) / 256, 256, 0, stream>>>(sums, (float*)d_out);
}

// Round 8
// 118.228 us; speedup vs baseline: 1.1792x; 1.1792x over previous
//
#include <hip/hip_runtime.h>
#include <hip/hip_bf16.h>

typedef __bf16 bf16x8 __attribute__((ext_vector_type(8)));
typedef float floatx4 __attribute__((ext_vector_type(4)));
typedef unsigned short u16;
typedef unsigned int u32;

#define HW 196      // 14*14
#define NB 8
#define NC 128
#define CL 480      // xfe row stride (u16)
#define WROW 12544  // u32 per (b,a1) row of W (= 25088 bf16 = 128c * 196p)

// ws offsets (bytes)
#define OFF_XFRSW 0            // 8 * 3584 uint4 = 458752 B  (A in MFMA-frag order)
#define OFF_XFE   458752       // 8*128*8*480*2 = 7864320 B  (8 shift-copies / row)
#define OFF_W     8323072      // 12845056 B
#define OFF_Y     21168160     // 8*128*256*4 = 1048576 B   (post-ReLU conv out, fp32)
#define OFF_XBT   22216736     // 8*256*512*2 = 2097152 B   (x^T bf16: [b][pix][k])
#define OFF_WB    24313888     // 128*512*2   = 131072 B    (w bf16: [o][k])
#define OFF_PARTS 24444960     // 256*4 = 1024 B            (per-block sum partials)

// ---- Stage 0: cast x (transposed) and w to bf16 ----
// blocks 0..511: x-part; 512..543: w-part. 256 thr.
__global__ __launch_bounds__(256) void k_cast(const float* __restrict__ x,
                                              const float* __restrict__ wc,
                                              u16* __restrict__ xbT,
                                              u16* __restrict__ wb) {
  const int bid = blockIdx.x;
  const int t   = threadIdx.x;
  if (bid < 512) {
    const int gid = bid * 256 + t;
    const int pix = gid & 255;          // lanes -> consecutive pix: coalesced reads
    const int kc  = (gid >> 8) & 63;    // 8-k chunk
    const int b   = gid >> 14;
    union { u16 u[8]; uint4 v; } pk;
#pragma unroll
    for (int j = 0; j < 8; ++j) {
      union { __hip_bfloat16 h; u16 u; } cv;
      cv.h = __float2bfloat16(x[((size_t)(b * 512 + kc * 8 + j)) * 256 + pix]);
      pk.u[j] = cv.u;
    }
    ((uint4*)xbT)[(size_t)(b * 256 + pix) * 64 + kc] = pk.v;
  } else {
    const int wid = (bid - 512) * 256 + t;   // 0..8191, 8 elems each
    const float4* wf4 = (const float4*)wc;
    const float4 f0 = wf4[wid * 2], f1 = wf4[wid * 2 + 1];
    union { u16 u[8]; uint4 v; } pk;
    union { __hip_bfloat16 h; u16 u; } cv;
    cv.h = __float2bfloat16(f0.x); pk.u[0] = cv.u;
    cv.h = __float2bfloat16(f0.y); pk.u[1] = cv.u;
    cv.h = __float2bfloat16(f0.z); pk.u[2] = cv.u;
    cv.h = __float2bfloat16(f0.w); pk.u[3] = cv.u;
    cv.h = __float2bfloat16(f1.x); pk.u[4] = cv.u;
    cv.h = __float2bfloat16(f1.y); pk.u[5] = cv.u;
    cv.h = __float2bfloat16(f1.z); pk.u[6] = cv.u;
    cv.h = __float2bfloat16(f1.w); pk.u[7] = cv.u;
    ((uint4*)wb)[wid] = pk.v;
  }
}

// ---- Stage 1: 1x1-conv GEMM via MFMA 16x16x32 bf16 + ReLU -> Y[b][o][pix] fp32 ----
// grid (8 b, 16 pt-of-16-pix) = 128 blocks (R7 lesson: 32 blocks was latency-dead
// at ~40 us — block count is the latency-hiding lever at this tiny scale).
// 256 thr = 4 waves; wave handles o-tiles {2wv, 2wv+1}; 48 b128 loads/thread.
__global__ __launch_bounds__(256) void k_conv(const u16* __restrict__ xbT,
                                              const u16* __restrict__ wb,
                                              float* __restrict__ Y) {
  const int b  = blockIdx.x;
  const int pt = blockIdx.y;
  const int t  = threadIdx.x;
  const int lane = t & 63, wv = t >> 6;
  const int n = lane & 15, quad = lane >> 4;
  const int pix = pt * 16 + n;

  const u16* xrow = xbT + ((size_t)(b * 256) + pix) * 512 + quad * 8;
  const u16* wrow = wb + (size_t)n * 512 + quad * 8;

  floatx4 acc[2];
  acc[0] = (floatx4){0.f, 0.f, 0.f, 0.f};
  acc[1] = (floatx4){0.f, 0.f, 0.f, 0.f};

#pragma unroll
  for (int kb = 0; kb < 16; ++kb) {
    const bf16x8 bv = *(const bf16x8*)(xrow + kb * 32);
#pragma unroll
    for (int j = 0; j < 2; ++j) {
      const int at = wv * 2 + j;
      const bf16x8 av = *(const bf16x8*)(wrow + (size_t)(at * 16) * 512 + kb * 32);
      acc[j] = __builtin_amdgcn_mfma_f32_16x16x32_bf16(av, bv, acc[j], 0, 0, 0);
    }
  }

  // D[m=quad*4+rr][n] -> Y[b][o=(wv*2+j)*16+quad*4+rr][pix], fused ReLU
  float* Yb = Y + ((size_t)b * 128) * 256 + pix;
#pragma unroll
  for (int j = 0; j < 2; ++j)
#pragma unroll
    for (int rr = 0; rr < 4; ++rr)
      Yb[((wv * 2 + j) * 16 + quad * 4 + rr) * 256] = fmaxf(acc[j][rr], 0.f);
}

// ---- Stage 1b: 3x3 Gaussian blur + bf16 + operand repack; emits:
//  xfr_sw[b][kb7][at8][quad4][m16][j8]  = reversed row (A-operand, frag order)
//  xfe[b][c][S8][CL]                    = row_c[(m+S) mod 196] (B shift table)
// grid (8 b, 32 rg-of-4-rows), 256 thr = pixel.
__global__ __launch_bounds__(256) void k_blur(const float* __restrict__ Y,
                                              uint4* __restrict__ xfr_sw,
                                              u16* __restrict__ xfe) {
  const int b  = blockIdx.x;
  const int rg = blockIdx.y;       // rows rg*4 .. +3
  const int t  = threadIdx.x;      // pixel

  __shared__ float ybuf[4][256];
  __shared__ u16 ydup[4][592];     // blurred row bf16, replicated 3x (idx 0..587)

#pragma unroll
  for (int oo = 0; oo < 4; ++oo)
    ybuf[oo][t] = Y[((size_t)(b * 128) + rg * 4 + oo) * 256 + t];  // already ReLU'd
  __syncthreads();

  const float GC = 0.63661977236758138f;   // gaussian var 0.25
  const float GE = GC * 0.13533528323661270f;
  const float GD = GC * 0.018315638888734179f;

  if (t < HW) {
    const int h = t / 14, w2 = t - h * 14;
#pragma unroll
    for (int oo = 0; oo < 4; ++oo) {
      const float* yb = &ybuf[oo][h * 16 + w2];
      float v = GD * (yb[0] + yb[2] + yb[32] + yb[34])
              + GE * (yb[1] + yb[16] + yb[18] + yb[33])
              + GC * yb[17];
      union { __hip_bfloat16 h2; u16 u; } cv; cv.h2 = __float2bfloat16(v);
      ydup[oo][t] = cv.u; ydup[oo][t + 196] = cv.u; ydup[oo][t + 392] = cv.u;
    }
  }
  __syncthreads();

  // xfr_sw: per row 28 uint4 (g = kb*4+quad), Arev[k] = y[(196-k)%196], 0 for k>=196
  if (t < 112) {
    const int oo = t / 28;
    const int g  = t - oo * 28;
    const int kb = g >> 2, quad = g & 3;
    const int c  = rg * 4 + oo;
    const int at = c >> 4, m = c & 15;
    union { u16 u[8]; uint4 v; } pk;
#pragma unroll
    for (int j = 0; j < 8; ++j) {
      const int k = g * 8 + j;
      pk.u[j] = (k < HW) ? ydup[oo][HW - k] : (u16)0;
    }
    xfr_sw[b * 3584 + ((kb * 8 + at) * 4 + quad) * 16 + m] = pk.v;
  }

  // xfe: 4 rows x 8 shifts x 60 uint4
  uint4* xfe4 = (uint4*)xfe;
  for (int idx = t; idx < 4 * 8 * 60; idx += 256) {
    const int oo = idx / 480;
    const int rem = idx - oo * 480;
    const int S = rem / 60;
    const int g = rem - S * 60;
    const int c = rg * 4 + oo;
    union { u16 u[8]; uint4 v; } pk;
#pragma unroll
    for (int j = 0; j < 8; ++j) pk.u[j] = ydup[oo][g * 8 + j + S];  // <= 487 < 588
    xfe4[((size_t)(b * NC + c) * 8 + S) * 60 + g] = pk.v;
  }
}

// ---- Stage 2: circular correlation via MFMA 16x16x32; conflict-free LDS A,
// B direct-from-global (L1/L2-hot); in-reg 4:1 a-fold; bf16 W[b][a1][c*196+p] ----
// grid (8 b, 64 cpair); 256 threads = 4 waves.  (unchanged since R4)
__global__ __launch_bounds__(256, 2) void k_cooc(const uint4* __restrict__ xfr_sw,
                                                 const u16* __restrict__ xfe,
                                                 u32* __restrict__ W) {
  const int b     = blockIdx.x;
  const int cpair = blockIdx.y;
  const int t     = threadIdx.x;

  __shared__ __align__(16) uint4 Abuf[3584];   // 57344 B, frag order
  __shared__ __align__(16) u16 Obuf[32 * 200]; // 12800 B

  { // flat coalesced staging (xfr_sw is XCD-L2 resident)
    const uint4* src = xfr_sw + b * 3584;
    for (int j = t; j < 3584; j += 256) Abuf[j] = src[j];
  }
  __syncthreads();

  const int lane = t & 63;
  const int wv   = t >> 6;       // p-tiles {wv, wv+4, wv+8} (+12 for wave 0)
  const int n    = lane & 15;
  const int quad = lane >> 4;
  const u16* xbase = xfe + ((size_t)(b * NC) * 8) * CL + (n & 8) + quad * 8
                   + (size_t)(n & 7) * CL;

  for (int c2 = 0; c2 < 2; ++c2) {
    const int c = cpair * 2 + c2;
    const u16* xc = xbase + (size_t)c * (8 * CL);

    floatx4 acc[8][4];
#pragma unroll
    for (int at = 0; at < 8; ++at)
#pragma unroll
      for (int j = 0; j < 4; ++j) acc[at][j] = (floatx4){0.f, 0.f, 0.f, 0.f};

    for (int kb = 0; kb < 7; ++kb) {
      bf16x8 af[8];
#pragma unroll
      for (int at = 0; at < 8; ++at)   // lane-contiguous: base + lane*16B, no conflicts
        af[at] = *((const bf16x8*)&Abuf[(kb * 8 + at) * 64 + lane]);

#define DO_PT(JC)                                                                \
      {                                                                          \
        const int p0 = (wv + 4 * (JC)) * 16;                                     \
        const bf16x8 bv = *((const bf16x8*)&xc[p0 + kb * 32]);                   \
        _Pragma("unroll")                                                        \
        for (int at = 0; at < 8; ++at)                                           \
          acc[at][JC] = __builtin_amdgcn_mfma_f32_16x16x32_bf16(af[at], bv,      \
                                                                acc[at][JC], 0, 0, 0); \
      }
      DO_PT(0)
      DO_PT(1)
      DO_PT(2)
      if (wv == 0) { DO_PT(3) }
#undef DO_PT
    }

#define EPI(JC)                                                                  \
    {                                                                            \
      const int p = (wv + 4 * (JC)) * 16 + n;                                    \
      if (p < HW) {                                                              \
        _Pragma("unroll")                                                        \
        for (int a0t = 0; a0t < 2; ++a0t) {                                      \
          _Pragma("unroll")                                                      \
          for (int rr = 0; rr < 4; ++rr) {                                       \
            float v = fmaxf(fmaxf(acc[a0t][JC][rr], acc[a0t + 2][JC][rr]),       \
                            fmaxf(acc[a0t + 4][JC][rr], acc[a0t + 6][JC][rr]));  \
            const int a1 = a0t * 16 + quad * 4 + rr;                             \
            union { __hip_bfloat16 h; u16 u; } cv;                               \
            cv.h = __float2bfloat16(v);                                          \
            Obuf[a1 * 200 + p] = cv.u;                                           \
          }                                                                      \
        }                                                                        \
      }                                                                          \
    }
    EPI(0)
    EPI(1)
    EPI(2)
    if (wv == 0) { EPI(3) }
#undef EPI
    __syncthreads();

    { // coalesced store: 32 rows x 98 u32 into W[b][a1][c*98 + col]
      const u32* O32 = (const u32*)Obuf;
      u32* Wb = W + ((size_t)b * 32) * WROW + c * 98;
      for (int j = t; j < 32 * 98; j += 256) {
        const int row = (int)(((unsigned)j * 10700u) >> 20);   // j / 98
        const int col = j - row * 98;
        Wb[row * WROW + col] = O32[row * 100 + col];
      }
    }
    __syncthreads();
  }
}

// ---- Stage 3: per-slot max over 49 contributors (coalesced) + sqrt; per-block
// partial sums to parts[bid] (plain store — no atomics, no memset needed) ----
__global__ __launch_bounds__(256) void k_max(const u32* __restrict__ W,
                                             float* __restrict__ out,
                                             float* __restrict__ parts) {
  const int gid = blockIdx.x * 256 + threadIdx.x;   // 0..65535
  const int b  = gid >> 13;
  const int r0 = (gid & 8191) << 1;
  const u32* Wb = W + (size_t)b * 32 * WROW;

  float m0 = 0.f, m1 = 0.f;
#pragma unroll 4
  for (int a1 = 0; a1 < 32; ++a1) {
    const int s = (r0 - ((a1 * 8704) & 16383)) & 16383;   // even
    const u32 v = Wb[a1 * WROW + (s >> 1)];
    m0 = fmaxf(m0, __uint_as_float((v & 0xffffu) << 16));
    m1 = fmaxf(m1, __uint_as_float(v & 0xffff0000u));
    if (s < 8704) {   // second contributor s+16384 < 25088
      const u32 v2 = Wb[a1 * WROW + ((s + 16384) >> 1)];
      m0 = fmaxf(m0, __uint_as_float((v2 & 0xffffu) << 16));
      m1 = fmaxf(m1, __uint_as_float(v2 & 0xffff0000u));
    }
  }
  const int o = b * 16384 + r0;
  out[o]     = sqrtf(m0);
  out[o + 1] = sqrtf(m1);

  float s2 = m0 + m1;
#pragma unroll
  for (int off = 32; off > 0; off >>= 1) s2 += __shfl_down(s2, off, 64);
  __shared__ float part[4];
  if ((threadIdx.x & 63) == 0) part[threadIdx.x >> 6] = s2;
  __syncthreads();
  if (threadIdx.x == 0)
    parts[blockIdx.x] = part[0] + part[1] + part[2] + part[3];
}

// ---- Stage 4: normalize (sums batch's 32 partials in-register) ----
__global__ __launch_bounds__(256) void k_norm(const float* __restrict__ parts,
                                              float* __restrict__ out) {
  const int gid = blockIdx.x * 256 + threadIdx.x;
  const int b = gid >> 14;
  float s = 0.f;
#pragma unroll
  for (int i = 0; i < 32; ++i) s += parts[b * 32 + i];   // broadcast, L1-hot
  out[gid] = out[gid] / (s + 1e-11f);
}

extern "C" void kernel_launch(void* const* d_in, const int* in_sizes, int n_in,
                              void* d_out, int out_size, void* d_ws, size_t ws_size,
                              hipStream_t stream) {
  const float* x  = (const float*)d_in[0];   // (8,512,16,16) fp32
  const float* wc = (const float*)d_in[1];   // (128,512) fp32

  char* ws = (char*)d_ws;
  uint4* xfr_sw = (uint4*)(ws + OFF_XFRSW);
  u16*   xfe    = (u16*)(ws + OFF_XFE);
  u32*   W      = (u32*)(ws + OFF_W);
  float* Y      = (float*)(ws + OFF_Y);
  u16*   xbT    = (u16*)(ws + OFF_XBT);
  u16*   wb     = (u16*)(ws + OFF_WB);
  float* parts  = (float*)(ws + OFF_PARTS);

  k_cast<<<544, 256, 0, stream>>>(x, wc, xbT, wb);
  k_conv<<<dim3(NB, 16), 256, 0, stream>>>(xbT, wb, Y);
  k_blur<<<dim3(NB, 32), 256, 0, stream>>>(Y, xfr_sw, xfe);
  k_cooc<<<dim3(NB, 64), 256, 0, stream>>>(xfr_sw, xfe, W);
  k_max<<<256, 256, 0, stream>>>(W, (float*)d_out, parts);
  k_norm<<<(NB * 16384) / 256, 256, 0, stream>>>(parts, (float*)d_out);
}

// Round 9
// 108.503 us; speedup vs baseline: 1.2848x; 1.0896x over previous
//
#include <hip/hip_runtime.h>
#include <hip/hip_bf16.h>

typedef __bf16 bf16x8 __attribute__((ext_vector_type(8)));
typedef float floatx4 __attribute__((ext_vector_type(4)));
typedef unsigned short u16;
typedef unsigned int u32;

#define HW 196      // 14*14
#define NB 8
#define NC 128
#define CL 480      // xfe row stride (u16)
#define WROW 12544  // u32 per (b,a1) row of W (= 25088 bf16 = 128c * 196p)

// ws offsets (bytes)
#define OFF_XFRSW 0            // 8 * 3584 uint4 = 458752 B  (A in MFMA-frag order)
#define OFF_XFE   458752       // 8*128*8*480*2 = 7864320 B  (8 shift-copies / row)
#define OFF_W     8323072      // 12845056 B
#define OFF_Y     21168160     // 8*128*256*4 = 1048576 B   (post-ReLU conv out, fp32)
#define OFF_XBT   22216736     // 8*256*512*2 = 2097152 B   (x^T bf16: [b][pix][k])
#define OFF_WB    24313888     // 128*512*2   = 131072 B    (w bf16: [o][k])
#define OFF_PARTS 24444960     // 256*4 = 1024 B            (per-block sum partials)

// ---- Stage 0: cast x (transposed) and w to bf16 ----
// blocks 0..511: x-part; 512..543: w-part. 256 thr.
__global__ __launch_bounds__(256) void k_cast(const float* __restrict__ x,
                                              const float* __restrict__ wc,
                                              u16* __restrict__ xbT,
                                              u16* __restrict__ wb) {
  const int bid = blockIdx.x;
  const int t   = threadIdx.x;
  if (bid < 512) {
    const int gid = bid * 256 + t;
    const int pix = gid & 255;          // lanes -> consecutive pix: coalesced reads
    const int kc  = (gid >> 8) & 63;    // 8-k chunk
    const int b   = gid >> 14;
    union { u16 u[8]; uint4 v; } pk;
#pragma unroll
    for (int j = 0; j < 8; ++j) {
      union { __hip_bfloat16 h; u16 u; } cv;
      cv.h = __float2bfloat16(x[((size_t)(b * 512 + kc * 8 + j)) * 256 + pix]);
      pk.u[j] = cv.u;
    }
    ((uint4*)xbT)[(size_t)(b * 256 + pix) * 64 + kc] = pk.v;
  } else {
    const int wid = (bid - 512) * 256 + t;   // 0..8191, 8 elems each
    const float4* wf4 = (const float4*)wc;
    const float4 f0 = wf4[wid * 2], f1 = wf4[wid * 2 + 1];
    union { u16 u[8]; uint4 v; } pk;
    union { __hip_bfloat16 h; u16 u; } cv;
    cv.h = __float2bfloat16(f0.x); pk.u[0] = cv.u;
    cv.h = __float2bfloat16(f0.y); pk.u[1] = cv.u;
    cv.h = __float2bfloat16(f0.z); pk.u[2] = cv.u;
    cv.h = __float2bfloat16(f0.w); pk.u[3] = cv.u;
    cv.h = __float2bfloat16(f1.x); pk.u[4] = cv.u;
    cv.h = __float2bfloat16(f1.y); pk.u[5] = cv.u;
    cv.h = __float2bfloat16(f1.z); pk.u[6] = cv.u;
    cv.h = __float2bfloat16(f1.w); pk.u[7] = cv.u;
    ((uint4*)wb)[wid] = pk.v;
  }
}

// ---- Stage 1: 1x1-conv GEMM via MFMA 16x16x32 bf16 + ReLU -> Y[b][o][pix] fp32 ----
// grid (8 b, 16 pt) = 128 blocks; 256 thr = 4 waves; 48 b128 loads/thread.
__global__ __launch_bounds__(256) void k_conv(const u16* __restrict__ xbT,
                                              const u16* __restrict__ wb,
                                              float* __restrict__ Y) {
  const int b  = blockIdx.x;
  const int pt = blockIdx.y;
  const int t  = threadIdx.x;
  const int lane = t & 63, wv = t >> 6;
  const int n = lane & 15, quad = lane >> 4;
  const int pix = pt * 16 + n;

  const u16* xrow = xbT + ((size_t)(b * 256) + pix) * 512 + quad * 8;
  const u16* wrow = wb + (size_t)n * 512 + quad * 8;

  floatx4 acc[2];
  acc[0] = (floatx4){0.f, 0.f, 0.f, 0.f};
  acc[1] = (floatx4){0.f, 0.f, 0.f, 0.f};

#pragma unroll
  for (int kb = 0; kb < 16; ++kb) {
    const bf16x8 bv = *(const bf16x8*)(xrow + kb * 32);
#pragma unroll
    for (int j = 0; j < 2; ++j) {
      const int at = wv * 2 + j;
      const bf16x8 av = *(const bf16x8*)(wrow + (size_t)(at * 16) * 512 + kb * 32);
      acc[j] = __builtin_amdgcn_mfma_f32_16x16x32_bf16(av, bv, acc[j], 0, 0, 0);
    }
  }

  float* Yb = Y + ((size_t)b * 128) * 256 + pix;
#pragma unroll
  for (int j = 0; j < 2; ++j)
#pragma unroll
    for (int rr = 0; rr < 4; ++rr)
      Yb[((wv * 2 + j) * 16 + quad * 4 + rr) * 256] = fmaxf(acc[j][rr], 0.f);
}

// ---- Stage 1b: 3x3 Gaussian blur + bf16 + operand repack (unchanged) ----
__global__ __launch_bounds__(256) void k_blur(const float* __restrict__ Y,
                                              uint4* __restrict__ xfr_sw,
                                              u16* __restrict__ xfe) {
  const int b  = blockIdx.x;
  const int rg = blockIdx.y;       // rows rg*4 .. +3
  const int t  = threadIdx.x;      // pixel

  __shared__ float ybuf[4][256];
  __shared__ u16 ydup[4][592];     // blurred row bf16, replicated 3x (idx 0..587)

#pragma unroll
  for (int oo = 0; oo < 4; ++oo)
    ybuf[oo][t] = Y[((size_t)(b * 128) + rg * 4 + oo) * 256 + t];  // already ReLU'd
  __syncthreads();

  const float GC = 0.63661977236758138f;   // gaussian var 0.25
  const float GE = GC * 0.13533528323661270f;
  const float GD = GC * 0.018315638888734179f;

  if (t < HW) {
    const int h = t / 14, w2 = t - h * 14;
#pragma unroll
    for (int oo = 0; oo < 4; ++oo) {
      const float* yb = &ybuf[oo][h * 16 + w2];
      float v = GD * (yb[0] + yb[2] + yb[32] + yb[34])
              + GE * (yb[1] + yb[16] + yb[18] + yb[33])
              + GC * yb[17];
      union { __hip_bfloat16 h2; u16 u; } cv; cv.h2 = __float2bfloat16(v);
      ydup[oo][t] = cv.u; ydup[oo][t + 196] = cv.u; ydup[oo][t + 392] = cv.u;
    }
  }
  __syncthreads();

  // xfr_sw: per row 28 uint4 (g = kb*4+quad), Arev[k] = y[(196-k)%196], 0 for k>=196
  if (t < 112) {
    const int oo = t / 28;
    const int g  = t - oo * 28;
    const int kb = g >> 2, quad = g & 3;
    const int c  = rg * 4 + oo;
    const int at = c >> 4, m = c & 15;
    union { u16 u[8]; uint4 v; } pk;
#pragma unroll
    for (int j = 0; j < 8; ++j) {
      const int k = g * 8 + j;
      pk.u[j] = (k < HW) ? ydup[oo][HW - k] : (u16)0;
    }
    xfr_sw[b * 3584 + ((kb * 8 + at) * 4 + quad) * 16 + m] = pk.v;
  }

  // xfe: 4 rows x 8 shifts x 60 uint4
  uint4* xfe4 = (uint4*)xfe;
  for (int idx = t; idx < 4 * 8 * 60; idx += 256) {
    const int oo = idx / 480;
    const int rem = idx - oo * 480;
    const int S = rem / 60;
    const int g = rem - S * 60;
    const int c = rg * 4 + oo;
    union { u16 u[8]; uint4 v; } pk;
#pragma unroll
    for (int j = 0; j < 8; ++j) pk.u[j] = ydup[oo][g * 8 + j + S];  // <= 487 < 588
    xfe4[((size_t)(b * NC + c) * 8 + S) * 60 + g] = pk.v;
  }
}

// ---- Stage 2: circular correlation via MFMA (unchanged since R4) ----
__global__ __launch_bounds__(256, 2) void k_cooc(const uint4* __restrict__ xfr_sw,
                                                 const u16* __restrict__ xfe,
                                                 u32* __restrict__ W) {
  const int b     = blockIdx.x;
  const int cpair = blockIdx.y;
  const int t     = threadIdx.x;

  __shared__ __align__(16) uint4 Abuf[3584];   // 57344 B, frag order
  __shared__ __align__(16) u16 Obuf[32 * 200]; // 12800 B

  { // flat coalesced staging (xfr_sw is XCD-L2 resident)
    const uint4* src = xfr_sw + b * 3584;
    for (int j = t; j < 3584; j += 256) Abuf[j] = src[j];
  }
  __syncthreads();

  const int lane = t & 63;
  const int wv   = t >> 6;       // p-tiles {wv, wv+4, wv+8} (+12 for wave 0)
  const int n    = lane & 15;
  const int quad = lane >> 4;
  const u16* xbase = xfe + ((size_t)(b * NC) * 8) * CL + (n & 8) + quad * 8
                   + (size_t)(n & 7) * CL;

  for (int c2 = 0; c2 < 2; ++c2) {
    const int c = cpair * 2 + c2;
    const u16* xc = xbase + (size_t)c * (8 * CL);

    floatx4 acc[8][4];
#pragma unroll
    for (int at = 0; at < 8; ++at)
#pragma unroll
      for (int j = 0; j < 4; ++j) acc[at][j] = (floatx4){0.f, 0.f, 0.f, 0.f};

    for (int kb = 0; kb < 7; ++kb) {
      bf16x8 af[8];
#pragma unroll
      for (int at = 0; at < 8; ++at)   // lane-contiguous: base + lane*16B, no conflicts
        af[at] = *((const bf16x8*)&Abuf[(kb * 8 + at) * 64 + lane]);

#define DO_PT(JC)                                                                \
      {                                                                          \
        const int p0 = (wv + 4 * (JC)) * 16;                                     \
        const bf16x8 bv = *((const bf16x8*)&xc[p0 + kb * 32]);                   \
        _Pragma("unroll")                                                        \
        for (int at = 0; at < 8; ++at)                                           \
          acc[at][JC] = __builtin_amdgcn_mfma_f32_16x16x32_bf16(af[at], bv,      \
                                                                acc[at][JC], 0, 0, 0); \
      }
      DO_PT(0)
      DO_PT(1)
      DO_PT(2)
      if (wv == 0) { DO_PT(3) }
#undef DO_PT
    }

#define EPI(JC)                                                                  \
    {                                                                            \
      const int p = (wv + 4 * (JC)) * 16 + n;                                    \
      if (p < HW) {                                                              \
        _Pragma("unroll")                                                        \
        for (int a0t = 0; a0t < 2; ++a0t) {                                      \
          _Pragma("unroll")                                                      \
          for (int rr = 0; rr < 4; ++rr) {                                       \
            float v = fmaxf(fmaxf(acc[a0t][JC][rr], acc[a0t + 2][JC][rr]),       \
                            fmaxf(acc[a0t + 4][JC][rr], acc[a0t + 6][JC][rr]));  \
            const int a1 = a0t * 16 + quad * 4 + rr;                             \
            union { __hip_bfloat16 h; u16 u; } cv;                               \
            cv.h = __float2bfloat16(v);                                          \
            Obuf[a1 * 200 + p] = cv.u;                                           \
          }                                                                      \
        }                                                                        \
      }                                                                          \
    }
    EPI(0)
    EPI(1)
    EPI(2)
    if (wv == 0) { EPI(3) }
#undef EPI
    __syncthreads();

    { // coalesced store: 32 rows x 98 u32 into W[b][a1][c*98 + col]
      const u32* O32 = (const u32*)Obuf;
      u32* Wb = W + ((size_t)b * 32) * WROW + c * 98;
      for (int j = t; j < 32 * 98; j += 256) {
        const int row = (int)(((unsigned)j * 10700u) >> 20);   // j / 98
        const int col = j - row * 98;
        Wb[row * WROW + col] = O32[row * 100 + col];
      }
    }
    __syncthreads();
  }
}

__device__ __forceinline__ float blo(u32 v) { return __uint_as_float(v << 16); }
__device__ __forceinline__ float bhi(u32 v) { return __uint_as_float(v & 0xffff0000u); }

// ---- Stage 3 (R9 rewrite): per-slot max, vectorized uint4 with a1 lane-split ----
// Thread (octet, g): octet = 8 consecutive r (uint4-aligned: s = (8k - a1*8704)
// & 16383 stays 8-aligned), g = lane>>4 handles a1 in [8g, 8g+8). Cross-g
// combine via 2 shfl_xor rounds; g==0 lanes sqrt + 2x float4 store.
// 256 blocks x 256 thr; block bid covers octets bid*64..+63 (b = bid>>5).
__global__ __launch_bounds__(256) void k_max(const u32* __restrict__ W,
                                             float* __restrict__ out,
                                             float* __restrict__ parts) {
  const int t = threadIdx.x;
  const int wv = t >> 6, lane = t & 63;
  const int g = lane >> 4, ol = lane & 15;
  const int octet = blockIdx.x * 64 + wv * 16 + ol;   // 0..16383
  const int b  = octet >> 11;                          // 2048 octets / batch
  const int r0 = (octet & 2047) << 3;
  const uint4* Wb = (const uint4*)(W + (size_t)b * 32 * WROW);

  float m[8];
#pragma unroll
  for (int j = 0; j < 8; ++j) m[j] = 0.f;

#pragma unroll
  for (int k = 0; k < 8; ++k) {
    const int a1 = g * 8 + k;
    const int s = (r0 - ((a1 * 8704) & 16383)) & 16383;   // 8-aligned
    const uint4 v = Wb[(a1 * WROW + (s >> 1)) >> 2];
    m[0] = fmaxf(m[0], blo(v.x)); m[1] = fmaxf(m[1], bhi(v.x));
    m[2] = fmaxf(m[2], blo(v.y)); m[3] = fmaxf(m[3], bhi(v.y));
    m[4] = fmaxf(m[4], blo(v.z)); m[5] = fmaxf(m[5], bhi(v.z));
    m[6] = fmaxf(m[6], blo(v.w)); m[7] = fmaxf(m[7], bhi(v.w));
    if (s < 8704) {   // second contributor s+16384 < 25088
      const uint4 v2 = Wb[((a1 * WROW + (s >> 1)) >> 2) + 2048];
      m[0] = fmaxf(m[0], blo(v2.x)); m[1] = fmaxf(m[1], bhi(v2.x));
      m[2] = fmaxf(m[2], blo(v2.y)); m[3] = fmaxf(m[3], bhi(v2.y));
      m[4] = fmaxf(m[4], blo(v2.z)); m[5] = fmaxf(m[5], bhi(v2.z));
      m[6] = fmaxf(m[6], blo(v2.w)); m[7] = fmaxf(m[7], bhi(v2.w));
    }
  }

  // combine the 4 a1-groups (lanes stride 16)
#pragma unroll
  for (int j = 0; j < 8; ++j) {
    m[j] = fmaxf(m[j], __shfl_xor(m[j], 16, 64));
    m[j] = fmaxf(m[j], __shfl_xor(m[j], 32, 64));
  }

  float s2 = 0.f;
  if (g == 0) {
    float4 s0, s1;
    s0.x = sqrtf(m[0]); s0.y = sqrtf(m[1]); s0.z = sqrtf(m[2]); s0.w = sqrtf(m[3]);
    s1.x = sqrtf(m[4]); s1.y = sqrtf(m[5]); s1.z = sqrtf(m[6]); s1.w = sqrtf(m[7]);
    float4* op = (float4*)(out + (size_t)octet * 8);
    op[0] = s0; op[1] = s1;
    s2 = ((m[0] + m[1]) + (m[2] + m[3])) + ((m[4] + m[5]) + (m[6] + m[7]));
  }

  // per-batch sum of c_ij^2: wave reduce (non-g0 lanes carry 0) then block
#pragma unroll
  for (int off = 32; off > 0; off >>= 1) s2 += __shfl_down(s2, off, 64);
  __shared__ float part[4];
  if (lane == 0) part[wv] = s2;
  __syncthreads();
  if (t == 0)
    parts[blockIdx.x] = part[0] + part[1] + part[2] + part[3];
}

// ---- Stage 4: normalize (b via blockIdx -> wave-uniform -> s_load parts) ----
__global__ __launch_bounds__(256) void k_norm(const float* __restrict__ parts,
                                              float* __restrict__ out) {
  const int b = blockIdx.x >> 6;    // 64 blocks per batch, provably uniform
  const int gid = blockIdx.x * 256 + threadIdx.x;
  float s = 0.f;
#pragma unroll
  for (int i = 0; i < 32; ++i) s += parts[b * 32 + i];   // scalar loads, L1-hot
  out[gid] = out[gid] / (s + 1e-11f);
}

extern "C" void kernel_launch(void* const* d_in, const int* in_sizes, int n_in,
                              void* d_out, int out_size, void* d_ws, size_t ws_size,
                              hipStream_t stream) {
  const float* x  = (const float*)d_in[0];   // (8,512,16,16) fp32
  const float* wc = (const float*)d_in[1];   // (128,512) fp32

  char* ws = (char*)d_ws;
  uint4* xfr_sw = (uint4*)(ws + OFF_XFRSW);
  u16*   xfe    = (u16*)(ws + OFF_XFE);
  u32*   W      = (u32*)(ws + OFF_W);
  float* Y      = (float*)(ws + OFF_Y);
  u16*   xbT    = (u16*)(ws + OFF_XBT);
  u16*   wb     = (u16*)(ws + OFF_WB);
  float* parts  = (float*)(ws + OFF_PARTS);

  k_cast<<<544, 256, 0, stream>>>(x, wc, xbT, wb);
  k_conv<<<dim3(NB, 16), 256, 0, stream>>>(xbT, wb, Y);
  k_blur<<<dim3(NB, 32), 256, 0, stream>>>(Y, xfr_sw, xfe);
  k_cooc<<<dim3(NB, 64), 256, 0, stream>>>(xfr_sw, xfe, W);
  k_max<<<256, 256, 0, stream>>>(W, (float*)d_out, parts);
  k_norm<<<(NB * 16384) / 256, 256, 0, stream>>>(parts, (float*)d_out);
}